// Round 8
// baseline (585.752 us; speedup 1.0000x reference)
//
#include <hip/hip_runtime.h>
#include <math.h>

#define N_NODES 100000
#define N_EDGES 1600000
#define NBUK 391          // ceil(N/256) buckets of 256 consecutive dst nodes
#define PCHUNK 8192       // edges per partition block
#define NPBLK 196         // ceil(E/PCHUNK)
#define BCAP 5120         // per-bucket LDS capacity in csr_k (mean 4092, sigma 64 -> 16 sigma)

typedef unsigned short u16;
typedef unsigned char u8;
typedef __bf16 bf16x8 __attribute__((ext_vector_type(8)));
typedef float f32x4 __attribute__((ext_vector_type(4)));
typedef float f32x2 __attribute__((ext_vector_type(2)));

// ---- workspace layout (bytes), 16B-aligned ----
#define OFF_RP      0u          // int[N+1]
#define OFF_INVDEG  400016u     // float[N]
#define OFF_BHIST   800016u     // int[392]
#define OFF_BBASE   801600u     // int[392]
#define OFF_GCUR    803200u     // int[392]
#define OFF_PAIRS   804800u     // u32[E] packed (dst&255)<<24 | src  = 6.4 MB
#define OFF_COL     7204800u    // int[E]  (src-sorted within each node)
#define OFF_PACK    13604800u   // u16[131072] packed bf16 weight fragments
#define OFF_INP     13866944u   // u16[N*128] residual (pre-relu inProj), bf16
#define OFF_H       39466944u   // u16[N*128] h (in-place across layers), bf16
#define OFF_H8A     65066944u   // u8[N*128] fp8 copy of h (gather path), buffer A
#define OFF_H8B     77866944u   // u8[N*128] fp8 copy, buffer B
#define OFF_GL      90666944u   // u16[N*64] projected neighbor logits, bf16
#define OFF_GR      103466944u  // u16[N*64] projected root logits, bf16
#define OFF_MEAN    116266944u  // u16[N*128] aggregated mean, bf16
#define WS_NEEDED   141866944u

// packed-weight element offsets (u16 units)
#define PK_WP   0
#define PK_WL   16384
#define PK_WR   65536
#define PK_WLO  114688
#define PK_WRO  122880

__device__ __forceinline__ float bfl(unsigned u) {
  union { unsigned i; float f; } v; v.i = u << 16; return v.f;
}
__device__ __forceinline__ float bfh(unsigned u) {
  union { unsigned i; float f; } v; v.i = u & 0xFFFF0000u; return v.f;
}
__device__ __forceinline__ u16 f2b(float f) {       // RTNE
  union { float f; unsigned i; } v; v.f = f;
  unsigned r = (v.i + 0x7FFFu + ((v.i >> 16) & 1u)) >> 16;
  return (u16)r;
}

// ---------------- pack fp32 weights -> bf16 MFMA B-fragments ----------------
__global__ __launch_bounds__(256) void pack_weights_k(
    const float* __restrict__ Wp, const float* __restrict__ Wl,
    const float* __restrict__ Wr, const float* __restrict__ Wlo,
    const float* __restrict__ Wro, u16* __restrict__ P) {
  int t = blockIdx.x * 256 + threadIdx.x;
  if (t >= 16384) return;
  const float* W; u16* dst; int j; int NT;
  if (t < 2048)        { W = Wp;                    dst = P + PK_WP;                j = t;                 NT = 8; }
  else if (t < 8192)   { int m = (t - 2048) >> 11;  j = (t - 2048) & 2047;
                         W = Wl + (m << 14);        dst = P + PK_WL + (m << 14);    NT = 8; }
  else if (t < 14336)  { int m = (t - 8192) >> 11;  j = (t - 8192) & 2047;
                         W = Wr + (m << 14);        dst = P + PK_WR + (m << 14);    NT = 8; }
  else if (t < 15360)  { j = t - 14336;             W = Wlo;  dst = P + PK_WLO;     NT = 4; }
  else                 { j = t - 15360;             W = Wro;  dst = P + PK_WRO;     NT = 4; }
  int lane = j & 63;
  int nt, kt;
  if (NT == 8) { nt = (j >> 6) & 7; kt = j >> 9; }
  else         { nt = (j >> 6) & 3; kt = j >> 8; }
  int n  = nt * 16 + (lane & 15);
  int k0 = kt * 32 + ((lane >> 4) << 3);
  const float* s = W + n * 128 + k0;
  ushort4 lo = make_ushort4(f2b(s[0]), f2b(s[1]), f2b(s[2]), f2b(s[3]));
  ushort4 hi = make_ushort4(f2b(s[4]), f2b(s[5]), f2b(s[6]), f2b(s[7]));
  *(ushort4*)(dst + j * 8)     = lo;
  *(ushort4*)(dst + j * 8 + 4) = hi;
}

// ---------- bucket histogram ----------
__global__ __launch_bounds__(256) void bhist_k(const int* __restrict__ dst,
                                               int* __restrict__ bhist) {
  __shared__ int lc[NBUK];
  int t = threadIdx.x;
  for (int i = t; i < NBUK; i += 256) lc[i] = 0;
  __syncthreads();
  int base = blockIdx.x * 4096;
#pragma unroll
  for (int r = 0; r < 16; r++) {
    int i = base + r * 256 + t;
    if (i < N_EDGES) atomicAdd(&lc[dst[i] >> 8], 1);
  }
  __syncthreads();
  for (int i = t; i < NBUK; i += 256)
    if (lc[i]) atomicAdd(&bhist[i], lc[i]);
}

// ---------- single-block scan of bucket counts ----------
__global__ __launch_bounds__(512) void bscan_k(const int* __restrict__ bhist,
                                               int* __restrict__ bbase,
                                               int* __restrict__ gcur,
                                               int* __restrict__ rp) {
  __shared__ int s[512];
  int t = threadIdx.x;
  int v = (t < NBUK) ? bhist[t] : 0;
  s[t] = v;
  __syncthreads();
  for (int off = 1; off < 512; off <<= 1) {
    int u = (t >= off) ? s[t - off] : 0;
    __syncthreads();
    s[t] += u;
    __syncthreads();
  }
  if (t < NBUK) { int e = s[t] - v; bbase[t] = e; gcur[t] = e; }
  if (t == NBUK - 1) { bbase[NBUK] = s[t]; rp[N_NODES] = s[t]; }
}

// ---------- partition edges into bucket-contiguous packed u32 ----------
__global__ __launch_bounds__(256) void part_k(const int* __restrict__ src,
                                              const int* __restrict__ dst,
                                              int* __restrict__ gcur,
                                              unsigned* __restrict__ pairs) {
  __shared__ int lcnt[NBUK + 1];
  __shared__ int lofs[512];
  __shared__ int cur[NBUK];
  __shared__ int gslot[NBUK];
  __shared__ unsigned stag[PCHUNK];
  int t = threadIdx.x;
  for (int i = t; i < NBUK + 1; i += 256) lcnt[i] = 0;
  __syncthreads();
  int base = blockIdx.x * PCHUNK;
#pragma unroll
  for (int r = 0; r < PCHUNK / 256; r++) {
    int i = base + r * 256 + t;
    if (i < N_EDGES) atomicAdd(&lcnt[dst[i] >> 8], 1);
  }
  __syncthreads();
  {
    int e1 = t + 256;
    lofs[t]  = (t  <= NBUK) ? lcnt[t]  : 0;
    lofs[e1] = (e1 <= NBUK) ? lcnt[e1] : 0;
    __syncthreads();
    for (int off = 1; off < 512; off <<= 1) {
      int a0 = (t  >= off) ? lofs[t  - off] : 0;
      int a1 = (e1 >= off) ? lofs[e1 - off] : 0;
      __syncthreads();
      lofs[t] += a0; lofs[e1] += a1;
      __syncthreads();
    }
    int o0 = lofs[t]  - ((t  <= NBUK) ? lcnt[t]  : 0);
    int o1 = lofs[e1] - ((e1 <= NBUK) ? lcnt[e1] : 0);
    __syncthreads();
    lofs[t] = o0; lofs[e1] = o1;
    __syncthreads();
  }
  for (int i = t; i < NBUK; i += 256) cur[i] = lofs[i];
  __syncthreads();
#pragma unroll
  for (int r = 0; r < PCHUNK / 256; r++) {
    int i = base + r * 256 + t;
    if (i < N_EDGES) {
      int d = dst[i];
      int slot = atomicAdd(&cur[d >> 8], 1);
      stag[slot] = ((unsigned)(d & 255) << 24) | (unsigned)src[i];
    }
  }
  __syncthreads();
  for (int i = t; i < NBUK; i += 256)
    if (lcnt[i]) gslot[i] = atomicAdd(&gcur[i], lcnt[i]);
  __syncthreads();
  int total = lofs[NBUK];
  for (int p = t; p < total; p += 256) {
    // binary search bucket: lofs[b] <= p < lofs[b+1]
    int loB = 0, hiB = NBUK;
    while (hiB - loB > 1) {
      int mid = (loB + hiB) >> 1;
      if (lofs[mid] <= p) loB = mid; else hiB = mid;
    }
    pairs[gslot[loB] + (p - lofs[loB])] = stag[p];
  }
}

// ---------- per-bucket CSR finalize; col sorted by src within each node ----------
__global__ __launch_bounds__(256) void csr_k(const unsigned* __restrict__ pairs,
                                             const int* __restrict__ bbase,
                                             int* __restrict__ rp,
                                             float* __restrict__ invdeg,
                                             int* __restrict__ col) {
  __shared__ unsigned raw[BCAP];
  __shared__ unsigned srt[BCAP];
  __shared__ int cnt[256];
  __shared__ int scn[256];
  __shared__ int cur[256];
  int b = blockIdx.x, t = threadIdx.x;
  int lo = bbase[b], hi = bbase[b + 1];
  int len = hi - lo;
  bool fits = (len <= BCAP);
  cnt[t] = 0;
  __syncthreads();
  if (fits) {
    for (int i = t; i < len; i += 256) {
      unsigned e = pairs[lo + i];
      raw[i] = e;
      atomicAdd(&cnt[e >> 24], 1);
    }
  } else {
    for (int p = lo + t; p < hi; p += 256)
      atomicAdd(&cnt[pairs[p] >> 24], 1);
  }
  __syncthreads();
  int c = cnt[t];
  scn[t] = c;
  __syncthreads();
  for (int off = 1; off < 256; off <<= 1) {
    int v = (t >= off) ? scn[t - off] : 0;
    __syncthreads();
    scn[t] += v;
    __syncthreads();
  }
  int excl = scn[t] - c;
  int node = (b << 8) + t;
  if (node < N_NODES) {
    rp[node] = lo + excl;
    invdeg[node] = 1.0f / (float)(c > 1 ? c : 1);
  }
  cur[t] = fits ? excl : (lo + excl);
  __syncthreads();
  if (fits) {
    for (int i = t; i < len; i += 256) {
      unsigned e = raw[i];
      int slot = atomicAdd(&cur[e >> 24], 1);
      srt[slot] = e;
    }
    __syncthreads();
    // per-node insertion sort by src (low bits; high byte constant within run)
    for (int i = excl + 1; i < excl + c; i++) {
      unsigned key = srt[i];
      int j = i - 1;
      while (j >= excl && srt[j] > key) { srt[j + 1] = srt[j]; j--; }
      srt[j + 1] = key;
    }
    __syncthreads();
    for (int i = t; i < len; i += 256)
      col[lo + i] = (int)(srt[i] & 0xFFFFFFu);
  } else {
    for (int p = lo + t; p < hi; p += 256) {
      unsigned e = pairs[p];
      int slot = atomicAdd(&cur[e >> 24], 1);
      col[slot] = (int)(e & 0xFFFFFFu);
    }
  }
}

// ------- mean aggregation from fp8 rows: half-wave per node, 4B loads, x4 unroll -------
__global__ __launch_bounds__(256) void aggregate_fp8_k(const u8* __restrict__ h8,
                                                       const int* __restrict__ rp,
                                                       const int* __restrict__ col,
                                                       const float* __restrict__ invdeg,
                                                       u16* __restrict__ mean) {
  int node = blockIdx.x * 8 + (threadIdx.x >> 5);
  int lane = threadIdx.x & 31;
  if (node >= N_NODES) return;
  int beg = rp[node], end = rp[node + 1];
  const u8* hp = h8 + lane * 4;
  float a0 = 0.f, a1 = 0.f, a2 = 0.f, a3 = 0.f;
  int j = beg;
  for (; j + 3 < end; j += 4) {
    int s0 = col[j], s1 = col[j + 1], s2 = col[j + 2], s3 = col[j + 3];
    unsigned v0 = *(const unsigned*)(hp + ((long)s0 << 7));
    unsigned v1 = *(const unsigned*)(hp + ((long)s1 << 7));
    unsigned v2 = *(const unsigned*)(hp + ((long)s2 << 7));
    unsigned v3 = *(const unsigned*)(hp + ((long)s3 << 7));
    f32x2 p0 = __builtin_amdgcn_cvt_pk_f32_fp8(v0, false);
    f32x2 p1 = __builtin_amdgcn_cvt_pk_f32_fp8(v0, true);
    f32x2 p2 = __builtin_amdgcn_cvt_pk_f32_fp8(v1, false);
    f32x2 p3 = __builtin_amdgcn_cvt_pk_f32_fp8(v1, true);
    f32x2 p4 = __builtin_amdgcn_cvt_pk_f32_fp8(v2, false);
    f32x2 p5 = __builtin_amdgcn_cvt_pk_f32_fp8(v2, true);
    f32x2 p6 = __builtin_amdgcn_cvt_pk_f32_fp8(v3, false);
    f32x2 p7 = __builtin_amdgcn_cvt_pk_f32_fp8(v3, true);
    a0 += (p0[0] + p2[0]) + (p4[0] + p6[0]);
    a1 += (p0[1] + p2[1]) + (p4[1] + p6[1]);
    a2 += (p1[0] + p3[0]) + (p5[0] + p7[0]);
    a3 += (p1[1] + p3[1]) + (p5[1] + p7[1]);
  }
  for (; j < end; j++) {
    unsigned v0 = *(const unsigned*)(hp + ((long)col[j] << 7));
    f32x2 p0 = __builtin_amdgcn_cvt_pk_f32_fp8(v0, false);
    f32x2 p1 = __builtin_amdgcn_cvt_pk_f32_fp8(v0, true);
    a0 += p0[0]; a1 += p0[1]; a2 += p1[0]; a3 += p1[1];
  }
  float wd = invdeg[node];
  *(ushort4*)(mean + ((long)node << 7) + lane * 4) =
      make_ushort4(f2b(a0 * wd), f2b(a1 * wd), f2b(a2 * wd), f2b(a3 * wd));
}

// ------- inProj: z = x@WpT + bp; inp=bf16(z); h=bf16(relu(z)); h8=fp8(relu(z)) -------
__global__ __launch_bounds__(256) void inproj_mfma_k(
    const float* __restrict__ X, const u16* __restrict__ P,
    const float* __restrict__ bias,
    u16* __restrict__ inp, u16* __restrict__ hout, u8* __restrict__ h8out, int M) {
  __shared__ float zb[64 * 132];
  int tid = threadIdx.x;
  int w = tid >> 6, lane = tid & 63;
  int quad = lane >> 4, l15 = lane & 15;
  int m0 = blockIdx.x * 64;
  int rowa = m0 + w * 16 + l15; if (rowa > M - 1) rowa = M - 1;
  f32x4 acc[8] = {};
#pragma unroll
  for (int kt = 0; kt < 4; kt++) {
    const float* xr = X + (long)rowa * 128 + kt * 32 + quad * 8;
    float4 p0 = *(const float4*)xr;
    float4 p1 = *(const float4*)(xr + 4);
    union { ushort4 u4[2]; bf16x8 v; } fa;
    fa.u4[0] = make_ushort4(f2b(p0.x), f2b(p0.y), f2b(p0.z), f2b(p0.w));
    fa.u4[1] = make_ushort4(f2b(p1.x), f2b(p1.y), f2b(p1.z), f2b(p1.w));
    const u16* pb = P + ((kt * 8) * 64 + lane) * 8;
#pragma unroll
    for (int nt = 0; nt < 8; nt++) {
      bf16x8 bf = *(const bf16x8*)(pb + nt * 512);
      acc[nt] = __builtin_amdgcn_mfma_f32_16x16x32_bf16(fa.v, bf, acc[nt], 0, 0, 0);
    }
  }
#pragma unroll
  for (int nt = 0; nt < 8; nt++) {
    int c = nt * 16 + l15;
    float b = bias[c];
#pragma unroll
    for (int r = 0; r < 4; r++)
      zb[(w * 16 + quad * 4 + r) * 132 + c] = acc[nt][r] + b;
  }
  __syncthreads();
  int r = lane >> 2, seg = lane & 3;
  long grow = m0 + w * 16 + r;
  if (grow < M) {
    const float* zrow = &zb[(w * 16 + r) * 132 + seg * 32];
    u16* ip = inp + grow * 128 + seg * 32;
    u16* hp = hout + grow * 128 + seg * 32;
    u8*  qp = h8out + grow * 128 + seg * 32;
#pragma unroll
    for (int b = 0; b < 4; b++) {
      float zv[8];
      *(float4*)&zv[0] = *(const float4*)(zrow + b * 8);
      *(float4*)&zv[4] = *(const float4*)(zrow + b * 8 + 4);
      float rv[8];
#pragma unroll
      for (int jj = 0; jj < 8; jj++) rv[jj] = fmaxf(zv[jj], 0.f);
      *(ushort4*)(ip + b * 8)     = make_ushort4(f2b(zv[0]), f2b(zv[1]), f2b(zv[2]), f2b(zv[3]));
      *(ushort4*)(ip + b * 8 + 4) = make_ushort4(f2b(zv[4]), f2b(zv[5]), f2b(zv[6]), f2b(zv[7]));
      *(ushort4*)(hp + b * 8)     = make_ushort4(f2b(rv[0]), f2b(rv[1]), f2b(rv[2]), f2b(rv[3]));
      *(ushort4*)(hp + b * 8 + 4) = make_ushort4(f2b(rv[4]), f2b(rv[5]), f2b(rv[6]), f2b(rv[7]));
      unsigned q0 = 0, q1 = 0;
      q0 = __builtin_amdgcn_cvt_pk_fp8_f32(rv[0], rv[1], q0, false);
      q0 = __builtin_amdgcn_cvt_pk_fp8_f32(rv[2], rv[3], q0, true);
      q1 = __builtin_amdgcn_cvt_pk_fp8_f32(rv[4], rv[5], q1, false);
      q1 = __builtin_amdgcn_cvt_pk_fp8_f32(rv[6], rv[7], q1, true);
      *(uint2*)(qp + b * 8) = make_uint2(q0, q1);
    }
  }
}

// ------- SAGE layer (layers 1,2): h = bf16(relu(mean@Wl + bl + h@Wr) + 0.2*inp), in-place;
//         emits fp8 copy for next layer's gather -------
__global__ __launch_bounds__(256) void sage_mfma8_k(
    const u16* __restrict__ A0, const u16* __restrict__ P0,
    const u16* __restrict__ A1, const u16* __restrict__ P1,
    const float* __restrict__ bias, const u16* __restrict__ inp,
    u16* __restrict__ outp, u8* __restrict__ h8out, int M) {
  __shared__ float zb[64 * 132];
  int tid = threadIdx.x;
  int w = tid >> 6, lane = tid & 63;
  int quad = lane >> 4, l15 = lane & 15;
  int m0 = blockIdx.x * 64;
  int rowa = m0 + w * 16 + l15; if (rowa > M - 1) rowa = M - 1;
  f32x4 acc[8] = {};
#pragma unroll
  for (int kt = 0; kt < 4; kt++) {
    bf16x8 am = *(const bf16x8*)(A0 + (long)rowa * 128 + kt * 32 + quad * 8);
    bf16x8 ar = *(const bf16x8*)(A1 + (long)rowa * 128 + kt * 32 + quad * 8);
    const u16* pl = P0 + ((kt * 8) * 64 + lane) * 8;
    const u16* pr = P1 + ((kt * 8) * 64 + lane) * 8;
#pragma unroll
    for (int nt = 0; nt < 8; nt++) {
      bf16x8 b0 = *(const bf16x8*)(pl + nt * 512);
      bf16x8 b1 = *(const bf16x8*)(pr + nt * 512);
      acc[nt] = __builtin_amdgcn_mfma_f32_16x16x32_bf16(am, b0, acc[nt], 0, 0, 0);
      acc[nt] = __builtin_amdgcn_mfma_f32_16x16x32_bf16(ar, b1, acc[nt], 0, 0, 0);
    }
  }
#pragma unroll
  for (int nt = 0; nt < 8; nt++) {
    int c = nt * 16 + l15;
    float b = bias[c];
#pragma unroll
    for (int r = 0; r < 4; r++)
      zb[(w * 16 + quad * 4 + r) * 132 + c] = fmaxf(acc[nt][r] + b, 0.f);
  }
  __syncthreads();
  int r = lane >> 2, seg = lane & 3;
  long grow = m0 + w * 16 + r;
  if (grow < M) {
    const float* zrow = &zb[(w * 16 + r) * 132 + seg * 32];
    const u16* ip = inp + grow * 128 + seg * 32;
    u16* op = outp + grow * 128 + seg * 32;
#pragma unroll
    for (int b = 0; b < 4; b++) {
      float zv[8];
      *(float4*)&zv[0] = *(const float4*)(zrow + b * 8);
      *(float4*)&zv[4] = *(const float4*)(zrow + b * 8 + 4);
      uint2 iv0 = *(const uint2*)(ip + b * 8);
      uint2 iv1 = *(const uint2*)(ip + b * 8 + 4);
      float fv[8];
      fv[0] = zv[0] + 0.2f * bfl(iv0.x); fv[1] = zv[1] + 0.2f * bfh(iv0.x);
      fv[2] = zv[2] + 0.2f * bfl(iv0.y); fv[3] = zv[3] + 0.2f * bfh(iv0.y);
      fv[4] = zv[4] + 0.2f * bfl(iv1.x); fv[5] = zv[5] + 0.2f * bfh(iv1.x);
      fv[6] = zv[6] + 0.2f * bfl(iv1.y); fv[7] = zv[7] + 0.2f * bfh(iv1.y);
      *(ushort4*)(op + b * 8)     = make_ushort4(f2b(fv[0]), f2b(fv[1]), f2b(fv[2]), f2b(fv[3]));
      *(ushort4*)(op + b * 8 + 4) = make_ushort4(f2b(fv[4]), f2b(fv[5]), f2b(fv[6]), f2b(fv[7]));
      unsigned q0 = 0, q1 = 0;
      q0 = __builtin_amdgcn_cvt_pk_fp8_f32(fv[0], fv[1], q0, false);
      q0 = __builtin_amdgcn_cvt_pk_fp8_f32(fv[2], fv[3], q0, true);
      q1 = __builtin_amdgcn_cvt_pk_fp8_f32(fv[4], fv[5], q1, false);
      q1 = __builtin_amdgcn_cvt_pk_fp8_f32(fv[6], fv[7], q1, true);
      *(uint2*)(h8out + grow * 128 + seg * 32 + b * 8) = make_uint2(q0, q1);
    }
  }
}

// ------- layer 3 fused with output projection:
// h3 = relu(mean@Wl3 + bl3 + h@Wr3) + 0.2*inp  (bf16, LDS only — never hits global)
// gl = h3@WloT, gr = h3@WroT  (bf16 [N,64] each) -------
__global__ __launch_bounds__(256) void sage_out_k(
    const u16* __restrict__ A0, const u16* __restrict__ P0,
    const u16* __restrict__ A1, const u16* __restrict__ P1,
    const float* __restrict__ bias, const u16* __restrict__ inp,
    const u16* __restrict__ PLO, const u16* __restrict__ PRO,
    u16* __restrict__ gl, u16* __restrict__ gr, int M) {
  __shared__ float zb[64 * 132];       // 33 KB
  __shared__ u16 hb[64 * 136];         // 17 KB, bf16 h3 in row-major
  int tid = threadIdx.x;
  int w = tid >> 6, lane = tid & 63;
  int quad = lane >> 4, l15 = lane & 15;
  int m0 = blockIdx.x * 64;
  int rowa = m0 + w * 16 + l15; if (rowa > M - 1) rowa = M - 1;
  f32x4 acc[8] = {};
#pragma unroll
  for (int kt = 0; kt < 4; kt++) {
    bf16x8 am = *(const bf16x8*)(A0 + (long)rowa * 128 + kt * 32 + quad * 8);
    bf16x8 ar = *(const bf16x8*)(A1 + (long)rowa * 128 + kt * 32 + quad * 8);
    const u16* pl = P0 + ((kt * 8) * 64 + lane) * 8;
    const u16* pr = P1 + ((kt * 8) * 64 + lane) * 8;
#pragma unroll
    for (int nt = 0; nt < 8; nt++) {
      bf16x8 b0 = *(const bf16x8*)(pl + nt * 512);
      bf16x8 b1 = *(const bf16x8*)(pr + nt * 512);
      acc[nt] = __builtin_amdgcn_mfma_f32_16x16x32_bf16(am, b0, acc[nt], 0, 0, 0);
      acc[nt] = __builtin_amdgcn_mfma_f32_16x16x32_bf16(ar, b1, acc[nt], 0, 0, 0);
    }
  }
#pragma unroll
  for (int nt = 0; nt < 8; nt++) {
    int c = nt * 16 + l15;
    float b = bias[c];
#pragma unroll
    for (int r = 0; r < 4; r++)
      zb[(w * 16 + quad * 4 + r) * 132 + c] = fmaxf(acc[nt][r] + b, 0.f);
  }
  __syncthreads();
  {
    int r = lane >> 2, seg = lane & 3;
    int lrow = w * 16 + r;
    long grow = m0 + lrow;
    long srcrow = (grow < M) ? grow : (M - 1);
    const float* zrow = &zb[lrow * 132 + seg * 32];
    const u16* ip = inp + srcrow * 128 + seg * 32;
    u16* hrow = &hb[lrow * 136 + seg * 32];
#pragma unroll
    for (int b = 0; b < 4; b++) {
      float zv[8];
      *(float4*)&zv[0] = *(const float4*)(zrow + b * 8);
      *(float4*)&zv[4] = *(const float4*)(zrow + b * 8 + 4);
      uint2 iv0 = *(const uint2*)(ip + b * 8);
      uint2 iv1 = *(const uint2*)(ip + b * 8 + 4);
      float fv[8];
      fv[0] = zv[0] + 0.2f * bfl(iv0.x); fv[1] = zv[1] + 0.2f * bfh(iv0.x);
      fv[2] = zv[2] + 0.2f * bfl(iv0.y); fv[3] = zv[3] + 0.2f * bfh(iv0.y);
      fv[4] = zv[4] + 0.2f * bfl(iv1.x); fv[5] = zv[5] + 0.2f * bfh(iv1.x);
      fv[6] = zv[6] + 0.2f * bfl(iv1.y); fv[7] = zv[7] + 0.2f * bfh(iv1.y);
      *(ushort4*)(hrow + b * 8)     = make_ushort4(f2b(fv[0]), f2b(fv[1]), f2b(fv[2]), f2b(fv[3]));
      *(ushort4*)(hrow + b * 8 + 4) = make_ushort4(f2b(fv[4]), f2b(fv[5]), f2b(fv[6]), f2b(fv[7]));
    }
  }
  __syncthreads();
  // second MFMA stage: gl/gr from LDS h3
  f32x4 acc2[8] = {};
#pragma unroll
  for (int kt = 0; kt < 4; kt++) {
    bf16x8 af = *(const bf16x8*)&hb[(w * 16 + l15) * 136 + kt * 32 + quad * 8];
#pragma unroll
    for (int nt = 0; nt < 4; nt++) {
      bf16x8 b0 = *(const bf16x8*)(PLO + ((kt * 4 + nt) * 64 + lane) * 8);
      bf16x8 b1 = *(const bf16x8*)(PRO + ((kt * 4 + nt) * 64 + lane) * 8);
      acc2[nt]     = __builtin_amdgcn_mfma_f32_16x16x32_bf16(af, b0, acc2[nt], 0, 0, 0);
      acc2[4 + nt] = __builtin_amdgcn_mfma_f32_16x16x32_bf16(af, b1, acc2[4 + nt], 0, 0, 0);
    }
  }
  __syncthreads();
  // zb cols 0-63 = gl, 64-127 = gr
#pragma unroll
  for (int nt = 0; nt < 4; nt++) {
    int c = nt * 16 + l15;
#pragma unroll
    for (int r = 0; r < 4; r++) {
      zb[(w * 16 + quad * 4 + r) * 132 + c]      = acc2[nt][r];
      zb[(w * 16 + quad * 4 + r) * 132 + 64 + c] = acc2[4 + nt][r];
    }
  }
  __syncthreads();
  int r = lane >> 2, seg = lane & 3;
  long grow = m0 + w * 16 + r;
  if (grow < M) {
    const float* zrow = &zb[(w * 16 + r) * 132 + seg * 32];
    u16* dp = (seg < 2) ? (gl + grow * 64 + seg * 32) : (gr + grow * 64 + (seg - 2) * 32);
#pragma unroll
    for (int b = 0; b < 4; b++) {
      float zv[8];
      *(float4*)&zv[0] = *(const float4*)(zrow + b * 8);
      *(float4*)&zv[4] = *(const float4*)(zrow + b * 8 + 4);
      *(ushort4*)(dp + b * 8)     = make_ushort4(f2b(zv[0]), f2b(zv[1]), f2b(zv[2]), f2b(zv[3]));
      *(ushort4*)(dp + b * 8 + 4) = make_ushort4(f2b(zv[4]), f2b(zv[5]), f2b(zv[6]), f2b(zv[7]));
    }
  }
}

// ------- output finalize: out = log_softmax(mean(gl) + gr + blo), half-wave per node -------
__global__ __launch_bounds__(256) void out_final_k(
    const u16* __restrict__ gl, const u16* __restrict__ gr,
    const float* __restrict__ blo, const int* __restrict__ rp,
    const int* __restrict__ col, const float* __restrict__ invdeg,
    float* __restrict__ outp) {
  int node = blockIdx.x * 8 + (threadIdx.x >> 5);
  int lane = threadIdx.x & 31;
  if (node >= N_NODES) return;
  int beg = rp[node], end = rp[node + 1];
  const u16* glp = gl + lane * 2;
  float a0 = 0.f, a1 = 0.f;
  int j = beg;
  for (; j + 3 < end; j += 4) {
    int s0 = col[j], s1 = col[j + 1], s2 = col[j + 2], s3 = col[j + 3];
    unsigned v0 = *(const unsigned*)(glp + ((long)s0 << 6));
    unsigned v1 = *(const unsigned*)(glp + ((long)s1 << 6));
    unsigned v2 = *(const unsigned*)(glp + ((long)s2 << 6));
    unsigned v3 = *(const unsigned*)(glp + ((long)s3 << 6));
    a0 += (bfl(v0) + bfl(v1)) + (bfl(v2) + bfl(v3));
    a1 += (bfh(v0) + bfh(v1)) + (bfh(v2) + bfh(v3));
  }
  for (; j < end; j++) {
    unsigned v0 = *(const unsigned*)(glp + ((long)col[j] << 6));
    a0 += bfl(v0); a1 += bfh(v0);
  }
  float wd = invdeg[node];
  unsigned g = *(const unsigned*)(gr + (long)node * 64 + lane * 2);
  float z0 = a0 * wd + bfl(g) + blo[lane * 2];
  float z1 = a1 * wd + bfh(g) + blo[lane * 2 + 1];
  float mx = fmaxf(z0, z1);
#pragma unroll
  for (int off = 16; off >= 1; off >>= 1) mx = fmaxf(mx, __shfl_xor(mx, off, 32));
  float s = __expf(z0 - mx) + __expf(z1 - mx);
#pragma unroll
  for (int off = 16; off >= 1; off >>= 1) s += __shfl_xor(s, off, 32);
  float ro = mx + __logf(s);
  float2 o = make_float2(z0 - ro, z1 - ro);
  *(float2*)(outp + (long)node * 64 + lane * 2) = o;
}

extern "C" void kernel_launch(void* const* d_in, const int* in_sizes, int n_in,
                              void* d_out, int out_size, void* d_ws, size_t ws_size,
                              hipStream_t stream) {
  if (ws_size < (size_t)WS_NEEDED) return;
  const float* x   = (const float*)d_in[0];
  const int*   ei  = (const int*)d_in[1];
  const float* Wp  = (const float*)d_in[2];
  const float* bp  = (const float*)d_in[3];
  const float* Wl  = (const float*)d_in[4];
  const float* bl  = (const float*)d_in[5];
  const float* Wr  = (const float*)d_in[6];
  const float* Wlo = (const float*)d_in[7];
  const float* blo = (const float*)d_in[8];
  const float* Wro = (const float*)d_in[9];
  float* out = (float*)d_out;
  char* ws = (char*)d_ws;
  int*      rp     = (int*)(ws + OFF_RP);
  float*    invdeg = (float*)(ws + OFF_INVDEG);
  int*      bhist  = (int*)(ws + OFF_BHIST);
  int*      bbase  = (int*)(ws + OFF_BBASE);
  int*      gcur   = (int*)(ws + OFF_GCUR);
  unsigned* pairs  = (unsigned*)(ws + OFF_PAIRS);
  int*      col    = (int*)(ws + OFF_COL);
  u16*      pack   = (u16*)(ws + OFF_PACK);
  u16*      inp    = (u16*)(ws + OFF_INP);
  u16*      h      = (u16*)(ws + OFF_H);
  u8*       h8a    = (u8*)(ws + OFF_H8A);
  u8*       h8b    = (u8*)(ws + OFF_H8B);
  u16*      gl     = (u16*)(ws + OFF_GL);
  u16*      gr     = (u16*)(ws + OFF_GR);
  u16*      mean   = (u16*)(ws + OFF_MEAN);
  const int* srcv = ei;
  const int* dstv = ei + N_EDGES;

  hipMemsetAsync(ws + OFF_BHIST, 0, (NBUK + 1) * 4, stream);
  pack_weights_k<<<64, 256, 0, stream>>>(Wp, Wl, Wr, Wlo, Wro, pack);
  bhist_k<<<391, 256, 0, stream>>>(dstv, bhist);
  bscan_k<<<1, 512, 0, stream>>>(bhist, bbase, gcur, rp);
  part_k<<<NPBLK, 256, 0, stream>>>(srcv, dstv, gcur, pairs);
  csr_k<<<NBUK, 256, 0, stream>>>(pairs, bbase, rp, invdeg, col);

  int gblk = (N_NODES + 63) / 64;
  int fblk = (N_NODES + 7) / 8;

  inproj_mfma_k<<<gblk, 256, 0, stream>>>(x, pack + PK_WP, bp, inp, h, h8a, N_NODES);

  aggregate_fp8_k<<<fblk, 256, 0, stream>>>(h8a, rp, col, invdeg, mean);
  sage_mfma8_k<<<gblk, 256, 0, stream>>>(mean, pack + PK_WL, h, pack + PK_WR,
                                         bl, inp, h, h8b, N_NODES);
  aggregate_fp8_k<<<fblk, 256, 0, stream>>>(h8b, rp, col, invdeg, mean);
  sage_mfma8_k<<<gblk, 256, 0, stream>>>(mean, pack + PK_WL + 16384, h, pack + PK_WR + 16384,
                                         bl + 128, inp, h, h8a, N_NODES);
  aggregate_fp8_k<<<fblk, 256, 0, stream>>>(h8a, rp, col, invdeg, mean);
  sage_out_k<<<gblk, 256, 0, stream>>>(mean, pack + PK_WL + 32768, h, pack + PK_WR + 32768,
                                       bl + 256, inp, pack + PK_WLO, pack + PK_WRO,
                                       gl, gr, N_NODES);
  out_final_k<<<fblk, 256, 0, stream>>>(gl, gr, blo, rp, col, invdeg, out);
}

// Round 9
// 552.379 us; speedup vs baseline: 1.0604x; 1.0604x over previous
//
#include <hip/hip_runtime.h>
#include <math.h>

#define N_NODES 100000
#define N_EDGES 1600000
#define NBUK 391          // ceil(N/256) buckets of 256 consecutive dst nodes
#define PCHUNK 4096       // edges per partition block
#define NPBLK 391         // ceil(E/PCHUNK)
#define BCAP 5120         // per-bucket LDS capacity in csr_k (mean 4092, sigma 64 -> 16 sigma)

typedef unsigned short u16;
typedef unsigned char u8;
typedef __bf16 bf16x8 __attribute__((ext_vector_type(8)));
typedef float f32x4 __attribute__((ext_vector_type(4)));
typedef float f32x2 __attribute__((ext_vector_type(2)));

// ---- workspace layout (bytes), 16B-aligned ----
#define OFF_RP      0u          // int[N+1]
#define OFF_INVDEG  400016u     // float[N]
#define OFF_BHIST   800016u     // int[392]
#define OFF_BBASE   801600u     // int[392]
#define OFF_GCUR    803200u     // int[392]
#define OFF_PAIRS   804800u     // u32[E] packed (dst&255)<<24 | src  = 6.4 MB
#define OFF_COL     7204800u    // int[E]  (src-sorted within each node)
#define OFF_PACK    13604800u   // u16[131072] packed bf16 weight fragments
#define OFF_INP     13866944u   // u16[N*128] residual (pre-relu inProj), bf16
#define OFF_H       39466944u   // u16[N*128] h (in-place across layers), bf16
#define OFF_H8A     65066944u   // u8[N*128] fp8 copy of h (gather path), buffer A
#define OFF_H8B     77866944u   // u8[N*128] fp8 copy, buffer B
#define OFF_GL      90666944u   // u16[N*64] projected neighbor logits, bf16
#define OFF_GR      103466944u  // u16[N*64] projected root logits, bf16
#define OFF_MEAN    116266944u  // u16[N*128] aggregated mean, bf16
#define WS_NEEDED   141866944u

// packed-weight element offsets (u16 units)
#define PK_WP   0
#define PK_WL   16384
#define PK_WR   65536
#define PK_WLO  114688
#define PK_WRO  122880

__device__ __forceinline__ float bfl(unsigned u) {
  union { unsigned i; float f; } v; v.i = u << 16; return v.f;
}
__device__ __forceinline__ float bfh(unsigned u) {
  union { unsigned i; float f; } v; v.i = u & 0xFFFF0000u; return v.f;
}
__device__ __forceinline__ u16 f2b(float f) {       // RTNE
  union { float f; unsigned i; } v; v.f = f;
  unsigned r = (v.i + 0x7FFFu + ((v.i >> 16) & 1u)) >> 16;
  return (u16)r;
}

// ---------------- pack fp32 weights -> bf16 MFMA B-fragments ----------------
__global__ __launch_bounds__(256) void pack_weights_k(
    const float* __restrict__ Wp, const float* __restrict__ Wl,
    const float* __restrict__ Wr, const float* __restrict__ Wlo,
    const float* __restrict__ Wro, u16* __restrict__ P) {
  int t = blockIdx.x * 256 + threadIdx.x;
  if (t >= 16384) return;
  const float* W; u16* dst; int j; int NT;
  if (t < 2048)        { W = Wp;                    dst = P + PK_WP;                j = t;                 NT = 8; }
  else if (t < 8192)   { int m = (t - 2048) >> 11;  j = (t - 2048) & 2047;
                         W = Wl + (m << 14);        dst = P + PK_WL + (m << 14);    NT = 8; }
  else if (t < 14336)  { int m = (t - 8192) >> 11;  j = (t - 8192) & 2047;
                         W = Wr + (m << 14);        dst = P + PK_WR + (m << 14);    NT = 8; }
  else if (t < 15360)  { j = t - 14336;             W = Wlo;  dst = P + PK_WLO;     NT = 4; }
  else                 { j = t - 15360;             W = Wro;  dst = P + PK_WRO;     NT = 4; }
  int lane = j & 63;
  int nt, kt;
  if (NT == 8) { nt = (j >> 6) & 7; kt = j >> 9; }
  else         { nt = (j >> 6) & 3; kt = j >> 8; }
  int n  = nt * 16 + (lane & 15);
  int k0 = kt * 32 + ((lane >> 4) << 3);
  const float* s = W + n * 128 + k0;
  ushort4 lo = make_ushort4(f2b(s[0]), f2b(s[1]), f2b(s[2]), f2b(s[3]));
  ushort4 hi = make_ushort4(f2b(s[4]), f2b(s[5]), f2b(s[6]), f2b(s[7]));
  *(ushort4*)(dst + j * 8)     = lo;
  *(ushort4*)(dst + j * 8 + 4) = hi;
}

// ---------- bucket histogram ----------
__global__ __launch_bounds__(256) void bhist_k(const int* __restrict__ dst,
                                               int* __restrict__ bhist) {
  __shared__ int lc[NBUK];
  int t = threadIdx.x;
  for (int i = t; i < NBUK; i += 256) lc[i] = 0;
  __syncthreads();
  int base = blockIdx.x * 4096;
#pragma unroll
  for (int r = 0; r < 16; r++) {
    int i = base + r * 256 + t;
    if (i < N_EDGES) atomicAdd(&lc[dst[i] >> 8], 1);
  }
  __syncthreads();
  for (int i = t; i < NBUK; i += 256)
    if (lc[i]) atomicAdd(&bhist[i], lc[i]);
}

// ---------- single-block scan of bucket counts ----------
__global__ __launch_bounds__(512) void bscan_k(const int* __restrict__ bhist,
                                               int* __restrict__ bbase,
                                               int* __restrict__ gcur,
                                               int* __restrict__ rp) {
  __shared__ int s[512];
  int t = threadIdx.x;
  int v = (t < NBUK) ? bhist[t] : 0;
  s[t] = v;
  __syncthreads();
  for (int off = 1; off < 512; off <<= 1) {
    int u = (t >= off) ? s[t - off] : 0;
    __syncthreads();
    s[t] += u;
    __syncthreads();
  }
  if (t < NBUK) { int e = s[t] - v; bbase[t] = e; gcur[t] = e; }
  if (t == NBUK - 1) { bbase[NBUK] = s[t]; rp[N_NODES] = s[t]; }
}

// ---------- partition edges into bucket-contiguous packed u32 ----------
// sbuk[] records each staged slot's bucket -> pass 3 has no search chain.
__global__ __launch_bounds__(256) void part_k(const int* __restrict__ src,
                                              const int* __restrict__ dst,
                                              int* __restrict__ gcur,
                                              unsigned* __restrict__ pairs) {
  __shared__ int lcnt[NBUK + 1];
  __shared__ int lofs[512];
  __shared__ int cur[NBUK];
  __shared__ int gslot[NBUK];
  __shared__ unsigned stag[PCHUNK];
  __shared__ u16 sbuk[PCHUNK];
  int t = threadIdx.x;
  for (int i = t; i < NBUK + 1; i += 256) lcnt[i] = 0;
  __syncthreads();
  int base = blockIdx.x * PCHUNK;
#pragma unroll
  for (int r = 0; r < PCHUNK / 256; r++) {
    int i = base + r * 256 + t;
    if (i < N_EDGES) atomicAdd(&lcnt[dst[i] >> 8], 1);
  }
  __syncthreads();
  {
    int e1 = t + 256;
    lofs[t]  = (t  <= NBUK) ? lcnt[t]  : 0;
    lofs[e1] = (e1 <= NBUK) ? lcnt[e1] : 0;
    __syncthreads();
    for (int off = 1; off < 512; off <<= 1) {
      int a0 = (t  >= off) ? lofs[t  - off] : 0;
      int a1 = (e1 >= off) ? lofs[e1 - off] : 0;
      __syncthreads();
      lofs[t] += a0; lofs[e1] += a1;
      __syncthreads();
    }
    int o0 = lofs[t]  - ((t  <= NBUK) ? lcnt[t]  : 0);
    int o1 = lofs[e1] - ((e1 <= NBUK) ? lcnt[e1] : 0);
    __syncthreads();
    lofs[t] = o0; lofs[e1] = o1;
    __syncthreads();
  }
  for (int i = t; i < NBUK; i += 256) cur[i] = lofs[i];
  __syncthreads();
#pragma unroll
  for (int r = 0; r < PCHUNK / 256; r++) {
    int i = base + r * 256 + t;
    if (i < N_EDGES) {
      int d = dst[i];
      int b = d >> 8;
      int slot = atomicAdd(&cur[b], 1);
      stag[slot] = ((unsigned)(d & 255) << 24) | (unsigned)src[i];
      sbuk[slot] = (u16)b;
    }
  }
  __syncthreads();
  for (int i = t; i < NBUK; i += 256)
    if (lcnt[i]) gslot[i] = atomicAdd(&gcur[i], lcnt[i]);
  __syncthreads();
  int total = lofs[NBUK];
  for (int p = t; p < total; p += 256) {
    int b = sbuk[p];
    pairs[gslot[b] + (p - lofs[b])] = stag[p];
  }
}

// ---------- per-bucket CSR finalize; col sorted by src within each node ----------
__global__ __launch_bounds__(256) void csr_k(const unsigned* __restrict__ pairs,
                                             const int* __restrict__ bbase,
                                             int* __restrict__ rp,
                                             float* __restrict__ invdeg,
                                             int* __restrict__ col) {
  __shared__ unsigned srt[BCAP];
  __shared__ int cnt[256];
  __shared__ int scn[256];
  __shared__ int cur[256];
  int b = blockIdx.x, t = threadIdx.x;
  int lo = bbase[b], hi = bbase[b + 1];
  int len = hi - lo;
  bool fits = (len <= BCAP);
  cnt[t] = 0;
  __syncthreads();
  for (int p = lo + t; p < hi; p += 256)
    atomicAdd(&cnt[pairs[p] >> 24], 1);
  __syncthreads();
  int c = cnt[t];
  scn[t] = c;
  __syncthreads();
  for (int off = 1; off < 256; off <<= 1) {
    int v = (t >= off) ? scn[t - off] : 0;
    __syncthreads();
    scn[t] += v;
    __syncthreads();
  }
  int excl = scn[t] - c;
  int node = (b << 8) + t;
  if (node < N_NODES) {
    rp[node] = lo + excl;
    invdeg[node] = 1.0f / (float)(c > 1 ? c : 1);
  }
  cur[t] = excl;
  __syncthreads();
  for (int p = lo + t; p < hi; p += 256) {
    unsigned e = pairs[p];
    int slot = atomicAdd(&cur[e >> 24], 1);
    if (fits) srt[slot] = e;
    else      col[lo + slot] = (int)(e & 0xFFFFFFu);   // overflow: unsorted (perf-only)
  }
  if (fits) {
    __syncthreads();
    // per-node insertion sort by src (low bits; high byte constant within run)
    for (int i = excl + 1; i < excl + c; i++) {
      unsigned key = srt[i];
      int j = i - 1;
      while (j >= excl && srt[j] > key) { srt[j + 1] = srt[j]; j--; }
      srt[j + 1] = key;
    }
    __syncthreads();
    for (int i = t; i < len; i += 256)
      col[lo + i] = (int)(srt[i] & 0xFFFFFFu);
  }
}

// ------- mean aggregation from fp8 rows: half-wave per node, 4B loads, x4 unroll -------
__global__ __launch_bounds__(256) void aggregate_fp8_k(const u8* __restrict__ h8,
                                                       const int* __restrict__ rp,
                                                       const int* __restrict__ col,
                                                       const float* __restrict__ invdeg,
                                                       u16* __restrict__ mean) {
  int node = blockIdx.x * 8 + (threadIdx.x >> 5);
  int lane = threadIdx.x & 31;
  if (node >= N_NODES) return;
  int beg = rp[node], end = rp[node + 1];
  const u8* hp = h8 + lane * 4;
  float a0 = 0.f, a1 = 0.f, a2 = 0.f, a3 = 0.f;
  int j = beg;
  for (; j + 3 < end; j += 4) {
    int s0 = col[j], s1 = col[j + 1], s2 = col[j + 2], s3 = col[j + 3];
    unsigned v0 = *(const unsigned*)(hp + ((long)s0 << 7));
    unsigned v1 = *(const unsigned*)(hp + ((long)s1 << 7));
    unsigned v2 = *(const unsigned*)(hp + ((long)s2 << 7));
    unsigned v3 = *(const unsigned*)(hp + ((long)s3 << 7));
    f32x2 p0 = __builtin_amdgcn_cvt_pk_f32_fp8(v0, false);
    f32x2 p1 = __builtin_amdgcn_cvt_pk_f32_fp8(v0, true);
    f32x2 p2 = __builtin_amdgcn_cvt_pk_f32_fp8(v1, false);
    f32x2 p3 = __builtin_amdgcn_cvt_pk_f32_fp8(v1, true);
    f32x2 p4 = __builtin_amdgcn_cvt_pk_f32_fp8(v2, false);
    f32x2 p5 = __builtin_amdgcn_cvt_pk_f32_fp8(v2, true);
    f32x2 p6 = __builtin_amdgcn_cvt_pk_f32_fp8(v3, false);
    f32x2 p7 = __builtin_amdgcn_cvt_pk_f32_fp8(v3, true);
    a0 += (p0[0] + p2[0]) + (p4[0] + p6[0]);
    a1 += (p0[1] + p2[1]) + (p4[1] + p6[1]);
    a2 += (p1[0] + p3[0]) + (p5[0] + p7[0]);
    a3 += (p1[1] + p3[1]) + (p5[1] + p7[1]);
  }
  for (; j < end; j++) {
    unsigned v0 = *(const unsigned*)(hp + ((long)col[j] << 7));
    f32x2 p0 = __builtin_amdgcn_cvt_pk_f32_fp8(v0, false);
    f32x2 p1 = __builtin_amdgcn_cvt_pk_f32_fp8(v0, true);
    a0 += p0[0]; a1 += p0[1]; a2 += p1[0]; a3 += p1[1];
  }
  float wd = invdeg[node];
  *(ushort4*)(mean + ((long)node << 7) + lane * 4) =
      make_ushort4(f2b(a0 * wd), f2b(a1 * wd), f2b(a2 * wd), f2b(a3 * wd));
}

// ------- inProj: z = x@WpT + bp; inp=bf16(z); h=bf16(relu(z)); h8=fp8(relu(z)) -------
__global__ __launch_bounds__(256) void inproj_mfma_k(
    const float* __restrict__ X, const u16* __restrict__ P,
    const float* __restrict__ bias,
    u16* __restrict__ inp, u16* __restrict__ hout, u8* __restrict__ h8out, int M) {
  __shared__ float zb[64 * 132];
  int tid = threadIdx.x;
  int w = tid >> 6, lane = tid & 63;
  int quad = lane >> 4, l15 = lane & 15;
  int m0 = blockIdx.x * 64;
  int rowa = m0 + w * 16 + l15; if (rowa > M - 1) rowa = M - 1;
  f32x4 acc[8] = {};
#pragma unroll
  for (int kt = 0; kt < 4; kt++) {
    const float* xr = X + (long)rowa * 128 + kt * 32 + quad * 8;
    float4 p0 = *(const float4*)xr;
    float4 p1 = *(const float4*)(xr + 4);
    union { ushort4 u4[2]; bf16x8 v; } fa;
    fa.u4[0] = make_ushort4(f2b(p0.x), f2b(p0.y), f2b(p0.z), f2b(p0.w));
    fa.u4[1] = make_ushort4(f2b(p1.x), f2b(p1.y), f2b(p1.z), f2b(p1.w));
    const u16* pb = P + ((kt * 8) * 64 + lane) * 8;
#pragma unroll
    for (int nt = 0; nt < 8; nt++) {
      bf16x8 bf = *(const bf16x8*)(pb + nt * 512);
      acc[nt] = __builtin_amdgcn_mfma_f32_16x16x32_bf16(fa.v, bf, acc[nt], 0, 0, 0);
    }
  }
#pragma unroll
  for (int nt = 0; nt < 8; nt++) {
    int c = nt * 16 + l15;
    float b = bias[c];
#pragma unroll
    for (int r = 0; r < 4; r++)
      zb[(w * 16 + quad * 4 + r) * 132 + c] = acc[nt][r] + b;
  }
  __syncthreads();
  int r = lane >> 2, seg = lane & 3;
  long grow = m0 + w * 16 + r;
  if (grow < M) {
    const float* zrow = &zb[(w * 16 + r) * 132 + seg * 32];
    u16* ip = inp + grow * 128 + seg * 32;
    u16* hp = hout + grow * 128 + seg * 32;
    u8*  qp = h8out + grow * 128 + seg * 32;
#pragma unroll
    for (int b = 0; b < 4; b++) {
      float zv[8];
      *(float4*)&zv[0] = *(const float4*)(zrow + b * 8);
      *(float4*)&zv[4] = *(const float4*)(zrow + b * 8 + 4);
      float rv[8];
#pragma unroll
      for (int jj = 0; jj < 8; jj++) rv[jj] = fmaxf(zv[jj], 0.f);
      *(ushort4*)(ip + b * 8)     = make_ushort4(f2b(zv[0]), f2b(zv[1]), f2b(zv[2]), f2b(zv[3]));
      *(ushort4*)(ip + b * 8 + 4) = make_ushort4(f2b(zv[4]), f2b(zv[5]), f2b(zv[6]), f2b(zv[7]));
      *(ushort4*)(hp + b * 8)     = make_ushort4(f2b(rv[0]), f2b(rv[1]), f2b(rv[2]), f2b(rv[3]));
      *(ushort4*)(hp + b * 8 + 4) = make_ushort4(f2b(rv[4]), f2b(rv[5]), f2b(rv[6]), f2b(rv[7]));
      unsigned q0 = 0, q1 = 0;
      q0 = __builtin_amdgcn_cvt_pk_fp8_f32(rv[0], rv[1], q0, false);
      q0 = __builtin_amdgcn_cvt_pk_fp8_f32(rv[2], rv[3], q0, true);
      q1 = __builtin_amdgcn_cvt_pk_fp8_f32(rv[4], rv[5], q1, false);
      q1 = __builtin_amdgcn_cvt_pk_fp8_f32(rv[6], rv[7], q1, true);
      *(uint2*)(qp + b * 8) = make_uint2(q0, q1);
    }
  }
}

// ------- SAGE layer (layers 1,2): h = bf16(relu(mean@Wl + bl + h@Wr) + 0.2*inp), in-place;
//         emits fp8 copy for next layer's gather -------
__global__ __launch_bounds__(256) void sage_mfma8_k(
    const u16* __restrict__ A0, const u16* __restrict__ P0,
    const u16* __restrict__ A1, const u16* __restrict__ P1,
    const float* __restrict__ bias, const u16* __restrict__ inp,
    u16* __restrict__ outp, u8* __restrict__ h8out, int M) {
  __shared__ float zb[64 * 132];
  int tid = threadIdx.x;
  int w = tid >> 6, lane = tid & 63;
  int quad = lane >> 4, l15 = lane & 15;
  int m0 = blockIdx.x * 64;
  int rowa = m0 + w * 16 + l15; if (rowa > M - 1) rowa = M - 1;
  f32x4 acc[8] = {};
#pragma unroll
  for (int kt = 0; kt < 4; kt++) {
    bf16x8 am = *(const bf16x8*)(A0 + (long)rowa * 128 + kt * 32 + quad * 8);
    bf16x8 ar = *(const bf16x8*)(A1 + (long)rowa * 128 + kt * 32 + quad * 8);
    const u16* pl = P0 + ((kt * 8) * 64 + lane) * 8;
    const u16* pr = P1 + ((kt * 8) * 64 + lane) * 8;
#pragma unroll
    for (int nt = 0; nt < 8; nt++) {
      bf16x8 b0 = *(const bf16x8*)(pl + nt * 512);
      bf16x8 b1 = *(const bf16x8*)(pr + nt * 512);
      acc[nt] = __builtin_amdgcn_mfma_f32_16x16x32_bf16(am, b0, acc[nt], 0, 0, 0);
      acc[nt] = __builtin_amdgcn_mfma_f32_16x16x32_bf16(ar, b1, acc[nt], 0, 0, 0);
    }
  }
#pragma unroll
  for (int nt = 0; nt < 8; nt++) {
    int c = nt * 16 + l15;
    float b = bias[c];
#pragma unroll
    for (int r = 0; r < 4; r++)
      zb[(w * 16 + quad * 4 + r) * 132 + c] = fmaxf(acc[nt][r] + b, 0.f);
  }
  __syncthreads();
  int r = lane >> 2, seg = lane & 3;
  long grow = m0 + w * 16 + r;
  if (grow < M) {
    const float* zrow = &zb[(w * 16 + r) * 132 + seg * 32];
    const u16* ip = inp + grow * 128 + seg * 32;
    u16* op = outp + grow * 128 + seg * 32;
#pragma unroll
    for (int b = 0; b < 4; b++) {
      float zv[8];
      *(float4*)&zv[0] = *(const float4*)(zrow + b * 8);
      *(float4*)&zv[4] = *(const float4*)(zrow + b * 8 + 4);
      uint2 iv0 = *(const uint2*)(ip + b * 8);
      uint2 iv1 = *(const uint2*)(ip + b * 8 + 4);
      float fv[8];
      fv[0] = zv[0] + 0.2f * bfl(iv0.x); fv[1] = zv[1] + 0.2f * bfh(iv0.x);
      fv[2] = zv[2] + 0.2f * bfl(iv0.y); fv[3] = zv[3] + 0.2f * bfh(iv0.y);
      fv[4] = zv[4] + 0.2f * bfl(iv1.x); fv[5] = zv[5] + 0.2f * bfh(iv1.x);
      fv[6] = zv[6] + 0.2f * bfl(iv1.y); fv[7] = zv[7] + 0.2f * bfh(iv1.y);
      *(ushort4*)(op + b * 8)     = make_ushort4(f2b(fv[0]), f2b(fv[1]), f2b(fv[2]), f2b(fv[3]));
      *(ushort4*)(op + b * 8 + 4) = make_ushort4(f2b(fv[4]), f2b(fv[5]), f2b(fv[6]), f2b(fv[7]));
      unsigned q0 = 0, q1 = 0;
      q0 = __builtin_amdgcn_cvt_pk_fp8_f32(fv[0], fv[1], q0, false);
      q0 = __builtin_amdgcn_cvt_pk_fp8_f32(fv[2], fv[3], q0, true);
      q1 = __builtin_amdgcn_cvt_pk_fp8_f32(fv[4], fv[5], q1, false);
      q1 = __builtin_amdgcn_cvt_pk_fp8_f32(fv[6], fv[7], q1, true);
      *(uint2*)(h8out + grow * 128 + seg * 32 + b * 8) = make_uint2(q0, q1);
    }
  }
}

// ------- layer 3 fused with output projection:
// h3 = relu(mean@Wl3 + bl3 + h@Wr3) + 0.2*inp  (bf16, LDS only — never hits global)
// gl = h3@WloT, gr = h3@WroT  (bf16 [N,64] each) -------
__global__ __launch_bounds__(256) void sage_out_k(
    const u16* __restrict__ A0, const u16* __restrict__ P0,
    const u16* __restrict__ A1, const u16* __restrict__ P1,
    const float* __restrict__ bias, const u16* __restrict__ inp,
    const u16* __restrict__ PLO, const u16* __restrict__ PRO,
    u16* __restrict__ gl, u16* __restrict__ gr, int M) {
  __shared__ float zb[64 * 132];       // 33 KB
  __shared__ u16 hb[64 * 136];         // 17 KB, bf16 h3 in row-major
  int tid = threadIdx.x;
  int w = tid >> 6, lane = tid & 63;
  int quad = lane >> 4, l15 = lane & 15;
  int m0 = blockIdx.x * 64;
  int rowa = m0 + w * 16 + l15; if (rowa > M - 1) rowa = M - 1;
  f32x4 acc[8] = {};
#pragma unroll
  for (int kt = 0; kt < 4; kt++) {
    bf16x8 am = *(const bf16x8*)(A0 + (long)rowa * 128 + kt * 32 + quad * 8);
    bf16x8 ar = *(const bf16x8*)(A1 + (long)rowa * 128 + kt * 32 + quad * 8);
    const u16* pl = P0 + ((kt * 8) * 64 + lane) * 8;
    const u16* pr = P1 + ((kt * 8) * 64 + lane) * 8;
#pragma unroll
    for (int nt = 0; nt < 8; nt++) {
      bf16x8 b0 = *(const bf16x8*)(pl + nt * 512);
      bf16x8 b1 = *(const bf16x8*)(pr + nt * 512);
      acc[nt] = __builtin_amdgcn_mfma_f32_16x16x32_bf16(am, b0, acc[nt], 0, 0, 0);
      acc[nt] = __builtin_amdgcn_mfma_f32_16x16x32_bf16(ar, b1, acc[nt], 0, 0, 0);
    }
  }
#pragma unroll
  for (int nt = 0; nt < 8; nt++) {
    int c = nt * 16 + l15;
    float b = bias[c];
#pragma unroll
    for (int r = 0; r < 4; r++)
      zb[(w * 16 + quad * 4 + r) * 132 + c] = fmaxf(acc[nt][r] + b, 0.f);
  }
  __syncthreads();
  {
    int r = lane >> 2, seg = lane & 3;
    int lrow = w * 16 + r;
    long grow = m0 + lrow;
    long srcrow = (grow < M) ? grow : (M - 1);
    const float* zrow = &zb[lrow * 132 + seg * 32];
    const u16* ip = inp + srcrow * 128 + seg * 32;
    u16* hrow = &hb[lrow * 136 + seg * 32];
#pragma unroll
    for (int b = 0; b < 4; b++) {
      float zv[8];
      *(float4*)&zv[0] = *(const float4*)(zrow + b * 8);
      *(float4*)&zv[4] = *(const float4*)(zrow + b * 8 + 4);
      uint2 iv0 = *(const uint2*)(ip + b * 8);
      uint2 iv1 = *(const uint2*)(ip + b * 8 + 4);
      float fv[8];
      fv[0] = zv[0] + 0.2f * bfl(iv0.x); fv[1] = zv[1] + 0.2f * bfh(iv0.x);
      fv[2] = zv[2] + 0.2f * bfl(iv0.y); fv[3] = zv[3] + 0.2f * bfh(iv0.y);
      fv[4] = zv[4] + 0.2f * bfl(iv1.x); fv[5] = zv[5] + 0.2f * bfh(iv1.x);
      fv[6] = zv[6] + 0.2f * bfl(iv1.y); fv[7] = zv[7] + 0.2f * bfh(iv1.y);
      *(ushort4*)(hrow + b * 8)     = make_ushort4(f2b(fv[0]), f2b(fv[1]), f2b(fv[2]), f2b(fv[3]));
      *(ushort4*)(hrow + b * 8 + 4) = make_ushort4(f2b(fv[4]), f2b(fv[5]), f2b(fv[6]), f2b(fv[7]));
    }
  }
  __syncthreads();
  // second MFMA stage: gl/gr from LDS h3
  f32x4 acc2[8] = {};
#pragma unroll
  for (int kt = 0; kt < 4; kt++) {
    bf16x8 af = *(const bf16x8*)&hb[(w * 16 + l15) * 136 + kt * 32 + quad * 8];
#pragma unroll
    for (int nt = 0; nt < 4; nt++) {
      bf16x8 b0 = *(const bf16x8*)(PLO + ((kt * 4 + nt) * 64 + lane) * 8);
      bf16x8 b1 = *(const bf16x8*)(PRO + ((kt * 4 + nt) * 64 + lane) * 8);
      acc2[nt]     = __builtin_amdgcn_mfma_f32_16x16x32_bf16(af, b0, acc2[nt], 0, 0, 0);
      acc2[4 + nt] = __builtin_amdgcn_mfma_f32_16x16x32_bf16(af, b1, acc2[4 + nt], 0, 0, 0);
    }
  }
  __syncthreads();
  // zb cols 0-63 = gl, 64-127 = gr
#pragma unroll
  for (int nt = 0; nt < 4; nt++) {
    int c = nt * 16 + l15;
#pragma unroll
    for (int r = 0; r < 4; r++) {
      zb[(w * 16 + quad * 4 + r) * 132 + c]      = acc2[nt][r];
      zb[(w * 16 + quad * 4 + r) * 132 + 64 + c] = acc2[4 + nt][r];
    }
  }
  __syncthreads();
  int r = lane >> 2, seg = lane & 3;
  long grow = m0 + w * 16 + r;
  if (grow < M) {
    const float* zrow = &zb[(w * 16 + r) * 132 + seg * 32];
    u16* dp = (seg < 2) ? (gl + grow * 64 + seg * 32) : (gr + grow * 64 + (seg - 2) * 32);
#pragma unroll
    for (int b = 0; b < 4; b++) {
      float zv[8];
      *(float4*)&zv[0] = *(const float4*)(zrow + b * 8);
      *(float4*)&zv[4] = *(const float4*)(zrow + b * 8 + 4);
      *(ushort4*)(dp + b * 8)     = make_ushort4(f2b(zv[0]), f2b(zv[1]), f2b(zv[2]), f2b(zv[3]));
      *(ushort4*)(dp + b * 8 + 4) = make_ushort4(f2b(zv[4]), f2b(zv[5]), f2b(zv[6]), f2b(zv[7]));
    }
  }
}

// ------- output finalize: out = log_softmax(mean(gl) + gr + blo), half-wave per node -------
__global__ __launch_bounds__(256) void out_final_k(
    const u16* __restrict__ gl, const u16* __restrict__ gr,
    const float* __restrict__ blo, const int* __restrict__ rp,
    const int* __restrict__ col, const float* __restrict__ invdeg,
    float* __restrict__ outp) {
  int node = blockIdx.x * 8 + (threadIdx.x >> 5);
  int lane = threadIdx.x & 31;
  if (node >= N_NODES) return;
  int beg = rp[node], end = rp[node + 1];
  const u16* glp = gl + lane * 2;
  float a0 = 0.f, a1 = 0.f;
  int j = beg;
  for (; j + 3 < end; j += 4) {
    int s0 = col[j], s1 = col[j + 1], s2 = col[j + 2], s3 = col[j + 3];
    unsigned v0 = *(const unsigned*)(glp + ((long)s0 << 6));
    unsigned v1 = *(const unsigned*)(glp + ((long)s1 << 6));
    unsigned v2 = *(const unsigned*)(glp + ((long)s2 << 6));
    unsigned v3 = *(const unsigned*)(glp + ((long)s3 << 6));
    a0 += (bfl(v0) + bfl(v1)) + (bfl(v2) + bfl(v3));
    a1 += (bfh(v0) + bfh(v1)) + (bfh(v2) + bfh(v3));
  }
  for (; j < end; j++) {
    unsigned v0 = *(const unsigned*)(glp + ((long)col[j] << 6));
    a0 += bfl(v0); a1 += bfh(v0);
  }
  float wd = invdeg[node];
  unsigned g = *(const unsigned*)(gr + (long)node * 64 + lane * 2);
  float z0 = a0 * wd + bfl(g) + blo[lane * 2];
  float z1 = a1 * wd + bfh(g) + blo[lane * 2 + 1];
  float mx = fmaxf(z0, z1);
#pragma unroll
  for (int off = 16; off >= 1; off >>= 1) mx = fmaxf(mx, __shfl_xor(mx, off, 32));
  float s = __expf(z0 - mx) + __expf(z1 - mx);
#pragma unroll
  for (int off = 16; off >= 1; off >>= 1) s += __shfl_xor(s, off, 32);
  float ro = mx + __logf(s);
  float2 o = make_float2(z0 - ro, z1 - ro);
  *(float2*)(outp + (long)node * 64 + lane * 2) = o;
}

extern "C" void kernel_launch(void* const* d_in, const int* in_sizes, int n_in,
                              void* d_out, int out_size, void* d_ws, size_t ws_size,
                              hipStream_t stream) {
  if (ws_size < (size_t)WS_NEEDED) return;
  const float* x   = (const float*)d_in[0];
  const int*   ei  = (const int*)d_in[1];
  const float* Wp  = (const float*)d_in[2];
  const float* bp  = (const float*)d_in[3];
  const float* Wl  = (const float*)d_in[4];
  const float* bl  = (const float*)d_in[5];
  const float* Wr  = (const float*)d_in[6];
  const float* Wlo = (const float*)d_in[7];
  const float* blo = (const float*)d_in[8];
  const float* Wro = (const float*)d_in[9];
  float* out = (float*)d_out;
  char* ws = (char*)d_ws;
  int*      rp     = (int*)(ws + OFF_RP);
  float*    invdeg = (float*)(ws + OFF_INVDEG);
  int*      bhist  = (int*)(ws + OFF_BHIST);
  int*      bbase  = (int*)(ws + OFF_BBASE);
  int*      gcur   = (int*)(ws + OFF_GCUR);
  unsigned* pairs  = (unsigned*)(ws + OFF_PAIRS);
  int*      col    = (int*)(ws + OFF_COL);
  u16*      pack   = (u16*)(ws + OFF_PACK);
  u16*      inp    = (u16*)(ws + OFF_INP);
  u16*      h      = (u16*)(ws + OFF_H);
  u8*       h8a    = (u8*)(ws + OFF_H8A);
  u8*       h8b    = (u8*)(ws + OFF_H8B);
  u16*      gl     = (u16*)(ws + OFF_GL);
  u16*      gr     = (u16*)(ws + OFF_GR);
  u16*      mean   = (u16*)(ws + OFF_MEAN);
  const int* srcv = ei;
  const int* dstv = ei + N_EDGES;

  hipMemsetAsync(ws + OFF_BHIST, 0, (NBUK + 1) * 4, stream);
  pack_weights_k<<<64, 256, 0, stream>>>(Wp, Wl, Wr, Wlo, Wro, pack);
  bhist_k<<<391, 256, 0, stream>>>(dstv, bhist);
  bscan_k<<<1, 512, 0, stream>>>(bhist, bbase, gcur, rp);
  part_k<<<NPBLK, 256, 0, stream>>>(srcv, dstv, gcur, pairs);
  csr_k<<<NBUK, 256, 0, stream>>>(pairs, bbase, rp, invdeg, col);

  int gblk = (N_NODES + 63) / 64;
  int fblk = (N_NODES + 7) / 8;

  inproj_mfma_k<<<gblk, 256, 0, stream>>>(x, pack + PK_WP, bp, inp, h, h8a, N_NODES);

  aggregate_fp8_k<<<fblk, 256, 0, stream>>>(h8a, rp, col, invdeg, mean);
  sage_mfma8_k<<<gblk, 256, 0, stream>>>(mean, pack + PK_WL, h, pack + PK_WR,
                                         bl, inp, h, h8b, N_NODES);
  aggregate_fp8_k<<<fblk, 256, 0, stream>>>(h8b, rp, col, invdeg, mean);
  sage_mfma8_k<<<gblk, 256, 0, stream>>>(mean, pack + PK_WL + 16384, h, pack + PK_WR + 16384,
                                         bl + 128, inp, h, h8a, N_NODES);
  aggregate_fp8_k<<<fblk, 256, 0, stream>>>(h8a, rp, col, invdeg, mean);
  sage_out_k<<<gblk, 256, 0, stream>>>(mean, pack + PK_WL + 32768, h, pack + PK_WR + 32768,
                                       bl + 256, inp, pack + PK_WLO, pack + PK_WRO,
                                       gl, gr, N_NODES);
  out_final_k<<<fblk, 256, 0, stream>>>(gl, gr, blo, rp, col, invdeg, out);
}